// Round 7
// baseline (7384.639 us; speedup 1.0000x reference)
//
#include <hip/hip_runtime.h>
#include <hip/hip_bf16.h>
#include <stdint.h>

typedef __bf16 bf16x8 __attribute__((ext_vector_type(8)));
typedef float  f32x4  __attribute__((ext_vector_type(4)));
typedef unsigned short u16;

__device__ __forceinline__ u16 f2bf(float f) {
    return __builtin_bit_cast(u16, __float2bfloat16(f));
}

__device__ __forceinline__ void gload16(const void* g, void* l) {
    __builtin_amdgcn_global_load_lds(
        (const __attribute__((address_space(1))) void*)g,
        (__attribute__((address_space(3))) void*)l,
        16, 0, 0);
}

// ---------------- quantization pipeline ----------------

__global__ void zero3_k(unsigned int* p) {
    if (threadIdx.x < 3) p[threadIdx.x] = 0u;
}

__global__ void maxabs_k(const float* __restrict__ w, int n, unsigned int* __restrict__ out) {
    const int tid = threadIdx.x;
    float m = 0.f;
    for (int i = blockIdx.x * blockDim.x + tid; i < n; i += gridDim.x * blockDim.x)
        m = fmaxf(m, fabsf(w[i]));
    #pragma unroll
    for (int off = 32; off > 0; off >>= 1)
        m = fmaxf(m, __shfl_down(m, off));
    __shared__ float red[4];
    if ((tid & 63) == 0) red[tid >> 6] = m;
    __syncthreads();
    if (tid == 0) {
        m = fmaxf(fmaxf(red[0], red[1]), fmaxf(red[2], red[3]));
        atomicMax(out, __float_as_uint(m));  // all values >=0: uint order == float order
    }
}

// w_q = clip(rint(w/scale), -n, n) * scale, scale = max|w|/n  (all fp32, matches jnp)
__global__ void quant_k(const float* __restrict__ w, int n,
                        const unsigned int* __restrict__ maxbits, float qn,
                        u16* __restrict__ out) {
    const float scale = __uint_as_float(*maxbits) / qn;
    for (int i = blockIdx.x * blockDim.x + threadIdx.x; i < n; i += gridDim.x * blockDim.x) {
        float q = rintf(w[i] / scale);          // RNE == jnp.round
        q = fminf(qn, fmaxf(-qn, q));
        out[i] = f2bf(q * scale);
    }
}

__global__ void cvt_k(const float* __restrict__ x, u16* __restrict__ o, long n) {
    const long stride = (long)gridDim.x * blockDim.x * 4;
    for (long i = ((long)blockIdx.x * blockDim.x + threadIdx.x) * 4; i < n; i += stride) {
        float4 v = *(const float4*)(x + i);
        unsigned int lo = (unsigned int)f2bf(v.x) | ((unsigned int)f2bf(v.y) << 16);
        unsigned int hi = (unsigned int)f2bf(v.z) | ((unsigned int)f2bf(v.w) << 16);
        *(uint2*)(o + i) = make_uint2(lo, hi);
    }
}

// ---------------- GEMM: C = A(MxK) * B(NxK)^T + bias, LeakyReLU ----------------
// 256x256 tile, BK=32, 8 waves (2M x 4N), per-wave 128x64 = 8x4 16x16x32 frags.
// 2-deep LDS ring (2 x 32KB = 64KB) -> 2 blocks/CU co-resident: cross-block
// wave overlap (m114) fills the DS<->MFMA alternation gaps that serialized the
// 1-block/CU variants. ONE raw s_barrier + one vmcnt(0) per K-32 tile:
//   tile k: vmcnt(0) [stage(k) landed; issued a full tile ago]
//           s_barrier [all waves consumed slot (k+1)&1 during tile k-1]
//           STAGE(k+1) into freed slot; 12 frag ds_reads; 32 MFMA (setprio).
// Swizzle (conflict-verified R3): 16B-granule pos = (4*row+slot)%8; slot ^=
// (row>>1)&3 makes rows 0..7 cover all 8 positions; 2-way residual = free.
// XCD-bijective block swizzle (A-panels shared 8-way within an XCD).

#define STAGE(kt)                                                               \
  do {                                                                          \
    const size_t _gk = (size_t)(kt) * 32;                                       \
    u16* _d = &smem[(kt) & 1][0][0];                                            \
    gload16(gA + _gk,           _d + wave * 512);                               \
    gload16(gA + rowHalf + _gk, _d + 4096 + wave * 512);                        \
    gload16(gB + _gk,           _d + 8192 + wave * 512);                        \
    gload16(gB + rowHalf + _gk, _d + 12288 + wave * 512);                       \
  } while (0)

#define TILE(kt, DO_STAGE)                                                      \
  do {                                                                          \
    asm volatile("s_waitcnt vmcnt(0)" ::: "memory");   /* stage(kt) landed */   \
    __builtin_amdgcn_s_barrier();            /* slot (kt+1)&1 reads all done */ \
    asm volatile("" ::: "memory");                                              \
    if (DO_STAGE) STAGE((kt) + 1);                                              \
    const u16* _sA = &smem[(kt) & 1][0][0];                                     \
    const u16* _sB = &smem[(kt) & 1][1][0];                                     \
    bf16x8 _bf[4], _af[8];                                                      \
    _Pragma("unroll") for (int n = 0; n < 4; ++n)                               \
        _bf[n] = *(const bf16x8*)(_sB + boff + n * 512);                        \
    _Pragma("unroll") for (int m = 0; m < 8; ++m)                               \
        _af[m] = *(const bf16x8*)(_sA + aoff + m * 512);                        \
    __builtin_amdgcn_s_setprio(1);                                              \
    _Pragma("unroll") for (int m = 0; m < 8; ++m)                               \
      _Pragma("unroll") for (int n = 0; n < 4; ++n)                             \
        acc[m][n] = __builtin_amdgcn_mfma_f32_16x16x32_bf16(_af[m], _bf[n],     \
                                                            acc[m][n], 0, 0, 0);\
    __builtin_amdgcn_s_setprio(0);                                              \
    asm volatile("" ::: "memory");                                              \
  } while (0)

template<int BF16OUT>
__global__ __launch_bounds__(512, 4)
void gemm8p(const u16* __restrict__ A, const u16* __restrict__ B,
            const float* __restrict__ bias, void* __restrict__ Cv,
            int M, int Nn, int K)
{
    __shared__ __align__(128) u16 smem[2][2][8192];  // [ring][A|B][256 rows x 32 cols]

    const int tid  = threadIdx.x;
    const int lane = tid & 63;
    const int wave = tid >> 6;
    const int wm = wave >> 2;   // 0..1 -> row offset wm*128
    const int wn = wave & 3;    // 0..3 -> col offset wn*64

    // XCD-aware bijective swizzle (gridDim.x % 8 == 0 here)
    const int nbx = Nn >> 8;
    const int cpx = gridDim.x >> 3;
    const int bid = blockIdx.x;
    const int swz = (bid & 7) * cpx + (bid >> 3);
    const int bn = (swz % nbx) << 8;
    const int bm = (swz / nbx) << 8;

    // staging: thread t -> LDS row t/4 (of a 128-row half), 16B slot t%4;
    // source column pre-swizzled: slot_src = (t%4) ^ ((row>>1)&3)   (rule 21)
    const int srow = tid >> 2;
    const int scol = (((tid & 3) ^ ((srow >> 1) & 3)) << 3);
    const u16* gA = A + (size_t)(bm + srow) * K + scol;
    const u16* gB = B + (size_t)(bn + srow) * K + scol;
    const size_t rowHalf = (size_t)128 * K;

    // frag ds_read offsets (elems): row*32 + (kslot ^ ((row>>1)&3))*8
    // frag rows = base(mult of 16) + fr, so (row>>1)&3 == (lane>>1)&3
    const int fr = lane & 15;
    const int slotp = (((lane >> 4) ^ ((lane >> 1) & 3)) << 3);
    const int aoff = (wm * 128 + fr) * 32 + slotp;   // + m*512 per m-frag
    const int boff = (wn * 64  + fr) * 32 + slotp;   // + n*512 per n-frag

    f32x4 acc[8][4] = {};

    STAGE(0);
    const int NT = K >> 5;
    for (int k = 0; k < NT - 1; ++k)
        TILE(k, true);
    TILE(NT - 1, false);

    // ---- epilogue: scalar stores (R2-proven; write-combining handles 32B rows) ----
    // C/D frag layout (m89): col = lane&15, row = (lane>>4)*4 + j
    const int crow = (lane >> 4) << 2;
    const int ccol = lane & 15;
    #pragma unroll
    for (int n = 0; n < 4; ++n) {
        const int col = bn + wn * 64 + n * 16 + ccol;
        const float bv = bias[col];
        #pragma unroll
        for (int m = 0; m < 8; ++m) {
            const int row0 = bm + wm * 128 + m * 16 + crow;
            #pragma unroll
            for (int j = 0; j < 4; ++j) {
                float v = acc[m][n][j] + bv;
                v = (v >= 0.f) ? v : 0.01f * v;
                if (BF16OUT) {
                    ((u16*)Cv)[(size_t)(row0 + j) * Nn + col] = f2bf(v);
                } else {
                    ((float*)Cv)[(size_t)(row0 + j) * Nn + col] = v;
                }
            }
        }
    }
}

// ---------------- launch ----------------

extern "C" void kernel_launch(void* const* d_in, const int* in_sizes, int n_in,
                              void* d_out, int out_size, void* d_ws, size_t ws_size,
                              hipStream_t stream) {
    const float* x  = (const float*)d_in[0];
    const float* W0 = (const float*)d_in[1];
    const float* b0 = (const float*)d_in[2];
    const float* W1 = (const float*)d_in[3];
    const float* b1 = (const float*)d_in[4];
    const float* W2 = (const float*)d_in[5];
    const float* b2 = (const float*)d_in[6];

    const int N = 32768, D0 = 1024, D1 = 2048;

    char* ws = (char*)d_ws;
    u16* xbf = (u16*)ws;  ws += (size_t)N * D0 * 2;
    u16* h0  = (u16*)ws;  ws += (size_t)N * D1 * 2;
    u16* h1  = (u16*)ws;  ws += (size_t)N * D1 * 2;
    u16* w0q = (u16*)ws;  ws += (size_t)D1 * D0 * 2;
    u16* w1q = (u16*)ws;  ws += (size_t)D1 * D1 * 2;
    u16* w2q = (u16*)ws;  ws += (size_t)D1 * D1 * 2;
    unsigned int* scales = (unsigned int*)ws;

    zero3_k<<<1, 64, 0, stream>>>(scales);
    maxabs_k<<<256, 256, 0, stream>>>(W0, D1 * D0, scales + 0);
    maxabs_k<<<256, 256, 0, stream>>>(W1, D1 * D1, scales + 1);
    maxabs_k<<<256, 256, 0, stream>>>(W2, D1 * D1, scales + 2);
    quant_k<<<2048, 256, 0, stream>>>(W0, D1 * D0, scales + 0, 127.f, w0q);
    quant_k<<<2048, 256, 0, stream>>>(W1, D1 * D1, scales + 1, 7.f, w1q);
    quant_k<<<2048, 256, 0, stream>>>(W2, D1 * D1, scales + 2, 7.f, w2q);
    cvt_k<<<4096, 256, 0, stream>>>(x, xbf, (long)N * D0);

    const int blocks = (D1 / 256) * (N / 256);   // 8 * 128 = 1024, %8 == 0
    gemm8p<1><<<blocks, 512, 0, stream>>>(xbf, w0q, b0, h0, N, D1, D0);
    gemm8p<1><<<blocks, 512, 0, stream>>>(h0, w1q, b1, h1, N, D1, D1);
    gemm8p<0><<<blocks, 512, 0, stream>>>(h1, w2q, b2, d_out, N, D1, D1);
}

// Round 8
// 744.498 us; speedup vs baseline: 9.9190x; 9.9190x over previous
//
#include <hip/hip_runtime.h>
#include <hip/hip_bf16.h>
#include <stdint.h>

typedef __bf16 bf16x8 __attribute__((ext_vector_type(8)));
typedef float  f32x4  __attribute__((ext_vector_type(4)));
typedef unsigned short u16;

__device__ __forceinline__ u16 f2bf(float f) {
    return __builtin_bit_cast(u16, __float2bfloat16(f));
}

__device__ __forceinline__ void gload16(const void* g, void* l) {
    __builtin_amdgcn_global_load_lds(
        (const __attribute__((address_space(1))) void*)g,
        (__attribute__((address_space(3))) void*)l,
        16, 0, 0);
}

// ---------------- quantization pipeline ----------------

__global__ void zero3_k(unsigned int* p) {
    if (threadIdx.x < 3) p[threadIdx.x] = 0u;
}

__global__ void maxabs_k(const float* __restrict__ w, int n, unsigned int* __restrict__ out) {
    const int tid = threadIdx.x;
    float m = 0.f;
    for (int i = blockIdx.x * blockDim.x + tid; i < n; i += gridDim.x * blockDim.x)
        m = fmaxf(m, fabsf(w[i]));
    #pragma unroll
    for (int off = 32; off > 0; off >>= 1)
        m = fmaxf(m, __shfl_down(m, off));
    __shared__ float red[4];
    if ((tid & 63) == 0) red[tid >> 6] = m;
    __syncthreads();
    if (tid == 0) {
        m = fmaxf(fmaxf(red[0], red[1]), fmaxf(red[2], red[3]));
        atomicMax(out, __float_as_uint(m));  // all values >=0: uint order == float order
    }
}

// w_q = clip(rint(w/scale), -n, n) * scale, scale = max|w|/n  (all fp32, matches jnp)
__global__ void quant_k(const float* __restrict__ w, int n,
                        const unsigned int* __restrict__ maxbits, float qn,
                        u16* __restrict__ out) {
    const float scale = __uint_as_float(*maxbits) / qn;
    for (int i = blockIdx.x * blockDim.x + threadIdx.x; i < n; i += gridDim.x * blockDim.x) {
        float q = rintf(w[i] / scale);          // RNE == jnp.round
        q = fminf(qn, fmaxf(-qn, q));
        out[i] = f2bf(q * scale);
    }
}

__global__ void cvt_k(const float* __restrict__ x, u16* __restrict__ o, long n) {
    const long stride = (long)gridDim.x * blockDim.x * 4;
    for (long i = ((long)blockIdx.x * blockDim.x + threadIdx.x) * 4; i < n; i += stride) {
        float4 v = *(const float4*)(x + i);
        unsigned int lo = (unsigned int)f2bf(v.x) | ((unsigned int)f2bf(v.y) << 16);
        unsigned int hi = (unsigned int)f2bf(v.z) | ((unsigned int)f2bf(v.w) << 16);
        *(uint2*)(o + i) = make_uint2(lo, hi);
    }
}

// ---------------- GEMM: C = A(MxK) * B(NxK)^T + bias, LeakyReLU ----------------
// Faithful m201-geometry port: 256x256 tile, BK=64, 8 waves (2M x 4N),
// 16x16x32 MFMA, INTERLEAVED frags (A-frag m: row (m>>2)*128+(m&3)*32+wm*16;
// B-frag n: col n*64+wn*16) so each phase = one C-quadrant (mh,nh) reading
// exactly one A-half + one B-half. LDS 128KB: A[2dbuf][2half][128][64],
// B same at +64KB. Per K-64 tile: 4 phases, each {ds-read quadrant frags |
// stage ONE half-tile of kt+1 (order A0,B0,B1,A1) | counted vmcnt | barrier |
// lgkmcnt(0)+sched_barrier | setprio+16 MFMA | barrier}. Ledger: vmcnt(4) at
// mids of P0,P1,P3 (none at P2; never 0 mid-loop; 2-3 half-tiles in flight).
// Swizzle (R3-counter-verified family): granule g ^= (row>>1)&7, write side
// pre-swizzles the GLOBAL source (rule 21) -> frag reads 2 lanes/granule.

#define VM4   asm volatile("s_waitcnt vmcnt(4)" ::: "memory")
#define BARR  __builtin_amdgcn_s_barrier()
#define LGKM0 do { asm volatile("s_waitcnt lgkmcnt(0)" ::: "memory");          \
                   __builtin_amdgcn_sched_barrier(0); } while (0)
#define FENCE asm volatile("" ::: "memory")

// stage half-tile: ISA=1 -> A, h = row-half; dest linear, src col pre-swizzled
#define STG(kt, ISA, h)                                                        \
  do {                                                                         \
    const u16* _s = (ISA) ? gA : gB;                                           \
    u16* _d = smem + ((ISA) ? 0 : 32768) + (((kt) & 1) << 14) + ((h) << 13)    \
              + wave * 512;                                                    \
    const size_t _go = (size_t)((h) * 128) * K + (size_t)(kt) * 64;            \
    gload16(_s + _go,                 _d);                                     \
    gload16(_s + _go + (size_t)64 * K, _d + 4096);                             \
  } while (0)

#define RD_A(kt, mh)                                                           \
  do {                                                                         \
    const u16* _p = smem + (((kt) & 1) << 14) + ((mh) << 13) + rowA;           \
    _Pragma("unroll") for (int m2 = 0; m2 < 4; ++m2) {                         \
        afr[m2 * 2]     = *(const bf16x8*)(_p + m2 * 2048 + g0);               \
        afr[m2 * 2 + 1] = *(const bf16x8*)(_p + m2 * 2048 + g1);               \
    }                                                                          \
  } while (0)

#define RD_B(kt, nh, DST)                                                      \
  do {                                                                         \
    const u16* _p = smem + 32768 + (((kt) & 1) << 14) + ((nh) << 13) + rowB;   \
    _Pragma("unroll") for (int n2 = 0; n2 < 2; ++n2) {                         \
        DST[n2 * 2]     = *(const bf16x8*)(_p + n2 * 4096 + g0);               \
        DST[n2 * 2 + 1] = *(const bf16x8*)(_p + n2 * 4096 + g1);               \
    }                                                                          \
  } while (0)

#define MM(mh, nh, BS)                                                         \
  do {                                                                         \
    __builtin_amdgcn_s_setprio(1);                                             \
    _Pragma("unroll") for (int m2 = 0; m2 < 4; ++m2)                           \
      _Pragma("unroll") for (int n2 = 0; n2 < 2; ++n2) {                       \
        acc[(mh)*4+m2][(nh)*2+n2] = __builtin_amdgcn_mfma_f32_16x16x32_bf16(   \
            afr[m2*2],     BS[n2*2],   acc[(mh)*4+m2][(nh)*2+n2], 0, 0, 0);    \
        acc[(mh)*4+m2][(nh)*2+n2] = __builtin_amdgcn_mfma_f32_16x16x32_bf16(   \
            afr[m2*2+1],   BS[n2*2+1], acc[(mh)*4+m2][(nh)*2+n2], 0, 0, 0);    \
      }                                                                        \
    __builtin_amdgcn_s_setprio(0);                                             \
  } while (0)

template<int BF16OUT>
__global__ __launch_bounds__(512, 2)
void gemm8x(const u16* __restrict__ A, const u16* __restrict__ B,
            const float* __restrict__ bias, void* __restrict__ Cv,
            int M, int Nn, int K)
{
    __shared__ __align__(128) u16 smem[65536];  // A: [0,32768) B: [32768,65536)

    const int tid  = threadIdx.x;
    const int lane = tid & 63;
    const int wave = tid >> 6;
    const int wm = wave >> 2;   // 0..1
    const int wn = wave & 3;    // 0..3

    // XCD-aware bijective swizzle (gridDim.x % 8 == 0)
    const int nbx = Nn >> 8;
    const int cpx = gridDim.x >> 3;
    const int swz = (blockIdx.x & 7) * cpx + (blockIdx.x >> 3);
    const int bn = (swz % nbx) << 8;
    const int bm = (swz / nbx) << 8;

    // staging source: thread t covers row (t>>3) of a 64-row chunk, granule t&7;
    // source granule pre-swizzled: (t&7) ^ ((r>>1)&7) == (t&7) ^ ((t>>4)&7)
    const int scol = (((tid & 7) ^ ((tid >> 4) & 7)) << 3);
    const u16* gA = A + (size_t)(bm + (tid >> 3)) * K + scol;
    const u16* gB = B + (size_t)(bn + (tid >> 3)) * K + scol;

    // frag ds_read constants (u16 elems)
    const int fr = lane & 15;
    const int g0 = (((lane >> 4)    ) ^ (fr >> 1)) << 3;   // ks=0 granule
    const int g1 = (((lane >> 4) + 4) ^ (fr >> 1)) << 3;   // ks=1 granule
    const int rowA = (wm * 16 + fr) << 6;                  // + m2*2048 per m-frag
    const int rowB = (wn * 16 + fr) << 6;                  // + n2*4096 per n-frag

    f32x4 acc[8][4] = {};
    bf16x8 afr[8], b0f[4], b1f[4];

    const int NT = K >> 6;   // 16 or 32

    // prologue: tile 0's half-tiles in ledger order A0,B0,B1,A1
    STG(0, 1, 0); STG(0, 0, 0); STG(0, 0, 1); STG(0, 1, 1);
    VM4;                 // certify A0,B0 (s2,s3 = 4 gloads newer)
    BARR;

    for (int kt = 0; kt < NT - 1; ++kt) {
        // P0: quadrant (0,0)
        RD_A(kt, 0); RD_B(kt, 0, b0f);
        STG(kt + 1, 1, 0);
        VM4; BARR; LGKM0;
        MM(0, 0, b0f);
        FENCE; BARR;
        // P1: quadrant (0,1)
        RD_B(kt, 1, b1f);
        STG(kt + 1, 0, 0);
        VM4; BARR; LGKM0;
        MM(0, 1, b1f);
        FENCE; BARR;
        // P2: quadrant (1,0)
        RD_A(kt, 1);
        STG(kt + 1, 0, 1);
        BARR; LGKM0;
        MM(1, 0, b0f);
        FENCE; BARR;
        // P3: quadrant (1,1)
        STG(kt + 1, 1, 1);
        VM4; BARR;
        __builtin_amdgcn_sched_barrier(0);
        MM(1, 1, b1f);
        FENCE; BARR;
    }
    {   // last tile: no staging; drain ledger 2 -> 0
        const int kt = NT - 1;
        RD_A(kt, 0); RD_B(kt, 0, b0f);
        asm volatile("s_waitcnt vmcnt(2)" ::: "memory");
        BARR; LGKM0;
        MM(0, 0, b0f);
        FENCE; BARR;
        RD_B(kt, 1, b1f);
        asm volatile("s_waitcnt vmcnt(0)" ::: "memory");
        BARR; LGKM0;
        MM(0, 1, b1f);
        FENCE; BARR;
        RD_A(kt, 1);
        BARR; LGKM0;
        MM(1, 0, b0f);
        FENCE;
        __builtin_amdgcn_sched_barrier(0);
        MM(1, 1, b1f);
    }

    // ---- epilogue: scalar stores (R2-proven) ----
    // C/D frag layout (m89): col = lane&15, row = (lane>>4)*4 + j
    // interleaved frag map: row = (m>>2)*128 + (m&3)*32 + wm*16; col = n*64 + wn*16
    const int crow = (lane >> 4) << 2;
    const int ccol = lane & 15;
    #pragma unroll
    for (int n = 0; n < 4; ++n) {
        const int col = bn + n * 64 + wn * 16 + ccol;
        const float bv = bias[col];
        #pragma unroll
        for (int m = 0; m < 8; ++m) {
            const int row0 = bm + (m >> 2) * 128 + (m & 3) * 32 + wm * 16 + crow;
            #pragma unroll
            for (int j = 0; j < 4; ++j) {
                float v = acc[m][n][j] + bv;
                v = (v >= 0.f) ? v : 0.01f * v;
                if (BF16OUT) {
                    ((u16*)Cv)[(size_t)(row0 + j) * Nn + col] = f2bf(v);
                } else {
                    ((float*)Cv)[(size_t)(row0 + j) * Nn + col] = v;
                }
            }
        }
    }
}

// ---------------- launch ----------------

extern "C" void kernel_launch(void* const* d_in, const int* in_sizes, int n_in,
                              void* d_out, int out_size, void* d_ws, size_t ws_size,
                              hipStream_t stream) {
    const float* x  = (const float*)d_in[0];
    const float* W0 = (const float*)d_in[1];
    const float* b0 = (const float*)d_in[2];
    const float* W1 = (const float*)d_in[3];
    const float* b1 = (const float*)d_in[4];
    const float* W2 = (const float*)d_in[5];
    const float* b2 = (const float*)d_in[6];

    const int N = 32768, D0 = 1024, D1 = 2048;

    char* ws = (char*)d_ws;
    u16* xbf = (u16*)ws;  ws += (size_t)N * D0 * 2;
    u16* h0  = (u16*)ws;  ws += (size_t)N * D1 * 2;
    u16* h1  = (u16*)ws;  ws += (size_t)N * D1 * 2;
    u16* w0q = (u16*)ws;  ws += (size_t)D1 * D0 * 2;
    u16* w1q = (u16*)ws;  ws += (size_t)D1 * D1 * 2;
    u16* w2q = (u16*)ws;  ws += (size_t)D1 * D1 * 2;
    unsigned int* scales = (unsigned int*)ws;

    zero3_k<<<1, 64, 0, stream>>>(scales);
    maxabs_k<<<256, 256, 0, stream>>>(W0, D1 * D0, scales + 0);
    maxabs_k<<<256, 256, 0, stream>>>(W1, D1 * D1, scales + 1);
    maxabs_k<<<256, 256, 0, stream>>>(W2, D1 * D1, scales + 2);
    quant_k<<<2048, 256, 0, stream>>>(W0, D1 * D0, scales + 0, 127.f, w0q);
    quant_k<<<2048, 256, 0, stream>>>(W1, D1 * D1, scales + 1, 7.f, w1q);
    quant_k<<<2048, 256, 0, stream>>>(W2, D1 * D1, scales + 2, 7.f, w2q);
    cvt_k<<<4096, 256, 0, stream>>>(x, xbf, (long)N * D0);

    const int blocks = (D1 / 256) * (N / 256);   // 8 * 128 = 1024, %8 == 0
    gemm8x<1><<<blocks, 512, 0, stream>>>(xbf, w0q, b0, h0, N, D1, D0);
    gemm8x<1><<<blocks, 512, 0, stream>>>(h0, w1q, b1, h1, N, D1, D1);
    gemm8x<0><<<blocks, 512, 0, stream>>>(h1, w2q, b2, d_out, N, D1, D1);
}